// Round 4
// baseline (8602.837 us; speedup 1.0000x reference)
//
#include <hip/hip_runtime.h>
#include <hip/hip_bf16.h>

// Problem dims (fixed)
#define B_ 32
#define S_ 64
#define H_ 512
#define T_ 32
#define V_ 32000
#define NBLK 256

typedef __attribute__((ext_vector_type(8))) short bf16x8;
typedef __attribute__((ext_vector_type(4))) float f32x4;

static __device__ __forceinline__ unsigned short f2bf(float f) {
    unsigned int u = __float_as_uint(f);
    u += 0x7FFF + ((u >> 16) & 1);   // RNE
    return (unsigned short)(u >> 16);
}
static __device__ __forceinline__ float dot4(float4 a, float4 b) {
    return a.x * b.x + a.y * b.y + a.z * b.z + a.w * b.w;
}
static __device__ __forceinline__ float tanh_fast(float x) {
    x = fminf(fmaxf(x, -15.f), 15.f);
    float e = __expf(2.f * x);
    return (e - 1.f) / (e + 1.f);
}
static __device__ __forceinline__ float sigmoid_fast(float x) {
    return 1.f / (1.f + __expf(-x));
}

// ---------------------------------------------------------------------------
// Manual grid barrier: monotonic counter, agent-scope atomics + threadfence
// (release L2-writeback before arrive, acquire invalidate after). Only tid 0
// spins; bounded so a broken barrier degrades to wrong output, never a hang.
// ---------------------------------------------------------------------------
static __device__ __forceinline__ void gbar(unsigned* cnt, unsigned* epoch)
{
    __syncthreads();
    if (threadIdx.x == 0) {
        __threadfence();  // agent-scope release: flush my phase writes
        __hip_atomic_fetch_add(cnt, 1u, __ATOMIC_ACQ_REL, __HIP_MEMORY_SCOPE_AGENT);
        const unsigned tgt = (++(*epoch)) * NBLK;
        long spin = 0;
        while (__hip_atomic_load(cnt, __ATOMIC_ACQUIRE, __HIP_MEMORY_SCOPE_AGENT) < tgt) {
            if (++spin > (1L << 20)) break;  // safety valve
        }
        __threadfence();  // agent-scope acquire: invalidate stale cache
    }
    __syncthreads();
}

__global__ void k_zero(unsigned* cnt) { if (threadIdx.x == 0) *cnt = 0; }

// ---------------------------------------------------------------------------
// C[m,n] = sum_k A[m,k] * B[n,k] + bias[n]   (B rows have leading dim Bld)
// A: fp32 or bf16, row-major M x K. M%128==0, N%128==0, K%32==0.
// grid: (N/128, M/128) -- n fast so B-tiles are reused within an XCD.
// LDS rows padded to 40 shorts (bank rotation 20 -> 2-way aliasing, free).
// ---------------------------------------------------------------------------
#define LDP 40
template <bool A_BF16>
__global__ __launch_bounds__(256, 2)
void gemm_bt(const void* __restrict__ Av, const float* __restrict__ Bm,
             const float* __restrict__ bias, float* __restrict__ C,
             int M, int N, int K, int Bld)
{
    __shared__ unsigned short As[128 * LDP];
    __shared__ unsigned short Bs[128 * LDP];

    const int n0 = blockIdx.x * 128;
    const int m0 = blockIdx.y * 128;
    const int tid  = threadIdx.x;
    const int lane = tid & 63;
    const int wave = tid >> 6;
    const int wm   = (wave & 1) * 64;
    const int wn   = (wave >> 1) * 64;
    const int quad = lane >> 4;   // 0..3
    const int l16  = lane & 15;

    f32x4 acc[4][4];
#pragma unroll
    for (int i = 0; i < 4; i++)
#pragma unroll
        for (int j = 0; j < 4; j++) acc[i][j] = (f32x4){0.f, 0.f, 0.f, 0.f};

    const int r0 = tid >> 2;  // 0..63 (row group)
    const int q4 = tid & 3;   // 0..3  (k sub-chunk of 8)

    for (int k0 = 0; k0 < K; k0 += 32) {
        __syncthreads();
#pragma unroll
        for (int rr = 0; rr < 2; rr++) {
            const int row = r0 + rr * 64;
            if (A_BF16) {
                const unsigned short* A16 = (const unsigned short*)Av;
                const uint4 v = *(const uint4*)(A16 + (size_t)(m0 + row) * K + k0 + q4 * 8);
                *(uint4*)(&As[row * LDP + q4 * 8]) = v;
            } else {
                const float* A32 = (const float*)Av;
                const float4 s0 = *(const float4*)(A32 + (size_t)(m0 + row) * K + k0 + q4 * 8);
                const float4 s1 = *(const float4*)(A32 + (size_t)(m0 + row) * K + k0 + q4 * 8 + 4);
                unsigned short tmp[8] = {f2bf(s0.x), f2bf(s0.y), f2bf(s0.z), f2bf(s0.w),
                                         f2bf(s1.x), f2bf(s1.y), f2bf(s1.z), f2bf(s1.w)};
                *(uint4*)(&As[row * LDP + q4 * 8]) = *(uint4*)tmp;
            }
            const float4 t0 = *(const float4*)(Bm + (size_t)(n0 + row) * Bld + k0 + q4 * 8);
            const float4 t1 = *(const float4*)(Bm + (size_t)(n0 + row) * Bld + k0 + q4 * 8 + 4);
            unsigned short tb[8] = {f2bf(t0.x), f2bf(t0.y), f2bf(t0.z), f2bf(t0.w),
                                    f2bf(t1.x), f2bf(t1.y), f2bf(t1.z), f2bf(t1.w)};
            *(uint4*)(&Bs[row * LDP + q4 * 8]) = *(uint4*)tb;
        }
        __syncthreads();

        bf16x8 af[4], bfr[4];
#pragma unroll
        for (int i = 0; i < 4; i++)
            af[i] = *(const bf16x8*)(&As[(wm + 16 * i + l16) * LDP + quad * 8]);
#pragma unroll
        for (int j = 0; j < 4; j++)
            bfr[j] = *(const bf16x8*)(&Bs[(wn + 16 * j + l16) * LDP + quad * 8]);
#pragma unroll
        for (int i = 0; i < 4; i++)
#pragma unroll
            for (int j = 0; j < 4; j++)
                acc[i][j] = __builtin_amdgcn_mfma_f32_16x16x32_bf16(af[i], bfr[j], acc[i][j], 0, 0, 0);
    }

#pragma unroll
    for (int i = 0; i < 4; i++)
#pragma unroll
        for (int j = 0; j < 4; j++)
#pragma unroll
            for (int r = 0; r < 4; r++) {
                const int m = m0 + wm + 16 * i + quad * 4 + r;
                const int n = n0 + wn + 16 * j + l16;
                C[(size_t)m * N + n] = acc[i][j][r] + bias[n];
            }
}

// ---------------------------------------------------------------------------
// h0 split-K partials: thread = (b, j, c) c in 0..3, K-chunk 256 of K=1024.
// ---------------------------------------------------------------------------
__global__ void k_h0part(const float* __restrict__ ehid, const float* __restrict__ Wh,
                         float* __restrict__ h0p)
{
    const int o = blockIdx.x * 256 + threadIdx.x;  // 65536
    const int b = o & 31, j = (o >> 5) & 511, c = o >> 14;
    const float* x = ehid + b * 1024 + c * 256;
    const float* w = Wh + (size_t)j * 1024 + c * 256;
    float s = 0.f;
#pragma unroll 8
    for (int k = 0; k < 256; k += 4)
        s += dot4(*(const float4*)(x + k), *(const float4*)(w + k));
    h0p[c * 16384 + b * 512 + j] = s;
}

__global__ void k_h0fin(const float* __restrict__ h0p, const float* __restrict__ bh,
                        float* __restrict__ h)
{
    const int o = blockIdx.x * 256 + threadIdx.x;  // 16384
    h[o] = bh[o & 511] + h0p[o] + h0p[16384 + o] + h0p[32768 + o] + h0p[49152 + o];
}

// ---------------------------------------------------------------------------
// Gather teacher-forced embedding rows: Xemb[b*T+t, :] = emb[tok(b,t), :]
// ---------------------------------------------------------------------------
__global__ void k_gather(const float* __restrict__ emb, const int* __restrict__ tgt,
                         float* __restrict__ Xemb)
{
    const int o = blockIdx.x * 256 + threadIdx.x;  // 131072
    const int r = o >> 7, k4 = (o & 127) * 4;
    const int b = r >> 5, t = r & 31;
    const int tok = t ? tgt[b * T_ + t - 1] : 0;
    *(float4*)(Xemb + (size_t)r * 512 + k4) = *(const float4*)(emb + (size_t)tok * 512 + k4);
}

// ---------------------------------------------------------------------------
// Persistent scan kernel: all 32 steps, 3 manual grid barriers per step.
//  Phase A: q[32,512] (+Wa_b) and gh[32,1536] (+b_hh), K=512 over h.
//  Phase B: per-batch attention (WGs 0..31): scores+softmax+ctx+attn_out.
//  Phase C: gx over ctx (K=1024 split 4 ways, shuffle-reduce) + GRU update.
// 256 WGs x 256 threads (1 WG/CU).
// ---------------------------------------------------------------------------
struct ScanParams {
    const float* enc;    // [B,S,2H]
    const float* ua;     // [B*S, H]
    const float* Wa_w;   // [H,H]
    const float* Wa_b;   // [H]
    const float* Va_w;   // [1,H]
    const float* Va_b;   // [1]
    const float* W_hh;   // [3H,H]
    const float* b_hh;   // [3H]
    const float* W_ih;   // [3H,3H]
    const float* Gxe;    // [B*T,3H] emb-part + b_ih
    float* h;            // [B,H]
    float* q;            // [B,H]
    float* gh;           // [B,3H]
    float* ctx;          // [B,2H]
    float* attn;         // [B,T,S]
    float* hf;           // [B,H]
    unsigned short* Hall;// [B*T,H] bf16
    unsigned* bar;       // barrier counter
};

__global__ __launch_bounds__(256)
void k_scan(ScanParams p)
{
    const int wg  = blockIdx.x;   // 0..255
    const int tid = threadIdx.x;  // 0..255
    const int idx = wg * 256 + tid;
    unsigned epoch = 0;

    __shared__ float qs[512];
    __shared__ float parts[64][4];
    __shared__ float wsm[64];

    for (int t = 0; t < T_; t++) {
        // ---------------- Phase A: q + gh ----------------
        {
            const int b = idx & 31, jall = idx >> 5;  // jall 0..2047
            const float* x = p.h + b * 512;
            const float* w = (jall < 512) ? (p.Wa_w + (size_t)jall * 512)
                                          : (p.W_hh + (size_t)(jall - 512) * 512);
            float s = 0.f;
#pragma unroll 8
            for (int k = 0; k < 512; k += 4)
                s += dot4(*(const float4*)(x + k), *(const float4*)(w + k));
            if (jall < 512) p.q[b * 512 + jall] = s + p.Wa_b[jall];
            else {
                const int r = jall - 512;
                p.gh[b * 1536 + r] = s + p.b_hh[r];
            }
        }
        gbar(p.bar, &epoch);

        // ---------------- Phase B: attention (WGs 0..31) ----------------
        if (wg < 32) {
            const int b = wg;
            for (int i = tid; i < 512; i += 256) qs[i] = p.q[b * 512 + i];
            __syncthreads();

            const int s = tid >> 2, p4 = tid & 3;
            {
                const float* uar = p.ua + ((size_t)(b * 64 + s)) * 512 + p4 * 128;
                const float* vp = p.Va_w + p4 * 128;
                float acc = 0.f;
#pragma unroll 8
                for (int k = 0; k < 128; k += 4) {
                    float4 u4 = *(const float4*)(uar + k);
                    float4 v4 = *(const float4*)(vp + k);
                    float4 q4 = *(const float4*)(&qs[p4 * 128 + k]);
                    acc += v4.x * tanh_fast(q4.x + u4.x) + v4.y * tanh_fast(q4.y + u4.y)
                         + v4.z * tanh_fast(q4.z + u4.z) + v4.w * tanh_fast(q4.w + u4.w);
                }
                parts[s][p4] = acc;
            }
            __syncthreads();

            if (tid < 64) {
                float sc = parts[tid][0] + parts[tid][1] + parts[tid][2] + parts[tid][3]
                         + p.Va_b[0];
                float mx = sc;
                for (int off = 32; off; off >>= 1) mx = fmaxf(mx, __shfl_down(mx, off));
                mx = __shfl(mx, 0);
                float e = __expf(sc - mx);
                float sum = e;
                for (int off = 32; off; off >>= 1) sum += __shfl_down(sum, off);
                sum = __shfl(sum, 0);
                float w = e / sum;
                wsm[tid] = w;
                p.attn[((size_t)b * T_ + t) * 64 + tid] = w;
            }
            __syncthreads();

            {
                const int mm = tid * 4;
                float4 a = {0.f, 0.f, 0.f, 0.f};
                for (int s2 = 0; s2 < 64; s2++) {
                    const float w = wsm[s2];
                    const float4 e4 = *(const float4*)(p.enc + ((size_t)(b * 64 + s2)) * 1024 + mm);
                    a.x += w * e4.x; a.y += w * e4.y; a.z += w * e4.z; a.w += w * e4.w;
                }
                *(float4*)(p.ctx + b * 1024 + mm) = a;
            }
        }
        gbar(p.bar, &epoch);

        // ---------------- Phase C: gx + GRU finalize ----------------
        {
            const int pair = wg * 64 + (tid >> 2);  // 0..16383
            const int c = tid & 3;
            const int b = pair & 31, j = pair >> 5;  // j 0..511
            const float* x  = p.ctx + b * 1024 + c * 256;
            const float* w0 = p.W_ih + (size_t)j * 1536 + 512 + c * 256;
            const float* w1 = w0 + 512 * 1536;
            const float* w2 = w1 + 512 * 1536;
            float s0 = 0.f, s1 = 0.f, s2 = 0.f;
#pragma unroll 8
            for (int k = 0; k < 256; k += 4) {
                const float4 xv = *(const float4*)(x + k);
                s0 += dot4(xv, *(const float4*)(w0 + k));
                s1 += dot4(xv, *(const float4*)(w1 + k));
                s2 += dot4(xv, *(const float4*)(w2 + k));
            }
            // reduce across the 4 k-chunks (adjacent lanes)
            s0 += __shfl_down(s0, 1); s0 += __shfl_down(s0, 2);
            s1 += __shfl_down(s1, 1); s1 += __shfl_down(s1, 2);
            s2 += __shfl_down(s2, 1); s2 += __shfl_down(s2, 2);
            if (c == 0) {
                const int o = b * 512 + j;
                const float gh0 = p.gh[b * 1536 + j];
                const float gh1 = p.gh[b * 1536 + 512 + j];
                const float gh2 = p.gh[b * 1536 + 1024 + j];
                const float* gxe = p.Gxe + ((size_t)(b * T_ + t)) * 1536;
                const float gx0 = gxe[j] + s0;
                const float gx1 = gxe[512 + j] + s1;
                const float gx2 = gxe[1024 + j] + s2;
                const float r = sigmoid_fast(gx0 + gh0);
                const float z = sigmoid_fast(gx1 + gh1);
                const float n = tanh_fast(gx2 + r * gh2);
                const float hn = (1.f - z) * n + z * p.h[o];
                p.h[o] = hn;
                p.Hall[((size_t)b * T_ + t) * 512 + j] = f2bf(hn);
                if (t == T_ - 1) p.hf[o] = hn;
            }
        }
        gbar(p.bar, &epoch);
    }
}

// ---------------------------------------------------------------------------
// Online log_softmax over V=32000 per row, in place. One block per row.
// ---------------------------------------------------------------------------
__global__ void k_logsoftmax(float* __restrict__ logits)
{
    __shared__ float rm[4], rs[4];
    const int row = blockIdx.x;
    float* p = logits + (size_t)row * V_;
    const int tid = threadIdx.x;

    float m = -1e30f, s = 0.f;
    for (int i = tid * 4; i < V_; i += 1024) {
        const float4 x = *(const float4*)(p + i);
        const float m4 = fmaxf(fmaxf(x.x, x.y), fmaxf(x.z, x.w));
        const float mn = fmaxf(m, m4);
        s = s * __expf(m - mn) + __expf(x.x - mn) + __expf(x.y - mn)
          + __expf(x.z - mn) + __expf(x.w - mn);
        m = mn;
    }
    for (int off = 32; off; off >>= 1) {
        const float m2 = __shfl_down(m, off), s2 = __shfl_down(s, off);
        const float mn = fmaxf(m, m2);
        s = s * __expf(m - mn) + s2 * __expf(m2 - mn);
        m = mn;
    }
    if ((tid & 63) == 0) { rm[tid >> 6] = m; rs[tid >> 6] = s; }
    __syncthreads();
    const float M = fmaxf(fmaxf(rm[0], rm[1]), fmaxf(rm[2], rm[3]));
    const float S = rs[0] * __expf(rm[0] - M) + rs[1] * __expf(rm[1] - M)
                  + rs[2] * __expf(rm[2] - M) + rs[3] * __expf(rm[3] - M);
    const float lse = M + __logf(S);

    for (int i = tid * 4; i < V_; i += 1024) {
        float4 x = *(const float4*)(p + i);
        x.x -= lse; x.y -= lse; x.z -= lse; x.w -= lse;
        *(float4*)(p + i) = x;
    }
}

// ---------------------------------------------------------------------------
extern "C" void kernel_launch(void* const* d_in, const int* in_sizes, int n_in,
                              void* d_out, int out_size, void* d_ws, size_t ws_size,
                              hipStream_t stream)
{
    const float* enc   = (const float*)d_in[0];   // [B,S,2H]
    const float* ehid  = (const float*)d_in[1];   // [1,B,2H]
    const int*   tgt   = (const int*)d_in[2];     // [B,T]
    const float* emb   = (const float*)d_in[3];   // [V,H]
    const float* Wa_w  = (const float*)d_in[4];   // [H,H]
    const float* Wa_b  = (const float*)d_in[5];
    const float* Ua_w  = (const float*)d_in[6];   // [H,2H]
    const float* Ua_b  = (const float*)d_in[7];
    const float* Va_w  = (const float*)d_in[8];   // [1,H]
    const float* Va_b  = (const float*)d_in[9];   // [1]
    const float* W_ih  = (const float*)d_in[10];  // [3H,3H]
    const float* b_ih  = (const float*)d_in[11];
    const float* W_hh  = (const float*)d_in[12];  // [3H,H]
    const float* b_hh  = (const float*)d_in[13];
    const float* Wh    = (const float*)d_in[14];  // [H,2H]
    const float* bh    = (const float*)d_in[15];
    const float* out_w = (const float*)d_in[16];  // [V,H]
    const float* out_b = (const float*)d_in[17];  // [V]

    float* outp = (float*)d_out;
    float* lp   = outp;                 // [B,T,V] = 32,768,000 floats
    float* hf   = outp + 32768000;      // [1,B,H]
    float* attn = outp + 32784384;      // [B,T,S]

    // Transient scratch inside lp (dead before the logits GEMM writes lp):
    float* Gxe  = lp;                   // 1,572,864  [B*T,3H] emb-part + b_ih
    float* Xemb = lp + 1572864;         //   524,288  [B*T,H]
    float* h0p  = lp + 2097152;         //    65,536  (setup only)

    // Persistent ws (~5.8 MB)
    float* ws  = (float*)d_ws;
    float* h   = ws;                    // 16,384
    float* ctx = ws + 16384;            // 32,768
    float* q   = ws + 49152;            // 16,384
    float* gh  = ws + 65536;            // 49,152
    float* ua  = ws + 114688;           // 1,048,576  [B*S,H]
    unsigned short* Hall = (unsigned short*)(ws + 1163264);  // [B*T,H] bf16 (262,144 floats)
    unsigned* bar = (unsigned*)(ws + 1425472);               // barrier counter

    // ---- setup ----
    k_zero<<<1, 64, 0, stream>>>(bar);
    k_h0part<<<256, 256, 0, stream>>>(ehid, Wh, h0p);
    k_h0fin<<<64, 256, 0, stream>>>(h0p, bh, h);
    k_gather<<<512, 256, 0, stream>>>(emb, tgt, Xemb);
    gemm_bt<false><<<dim3(4, 16), 256, 0, stream>>>(enc, Ua_w, Ua_b, ua,
                                                    2048, 512, 1024, 1024);
    gemm_bt<false><<<dim3(12, 8), 256, 0, stream>>>(Xemb, W_ih, b_ih, Gxe,
                                                    1024, 1536, 512, 1536);

    // ---- persistent scan (manual grid barrier) ----
    ScanParams sp;
    sp.enc = enc; sp.ua = ua; sp.Wa_w = Wa_w; sp.Wa_b = Wa_b;
    sp.Va_w = Va_w; sp.Va_b = Va_b; sp.W_hh = W_hh; sp.b_hh = b_hh;
    sp.W_ih = W_ih; sp.Gxe = Gxe; sp.h = h; sp.q = q; sp.gh = gh;
    sp.ctx = ctx; sp.attn = attn; sp.hf = hf; sp.Hall = Hall; sp.bar = bar;
    k_scan<<<NBLK, 256, 0, stream>>>(sp);

    // ---- logits + log_softmax ----
    gemm_bt<true><<<dim3(250, 8), 256, 0, stream>>>(Hall, out_w, out_b, lp,
                                                    1024, V_, 512, 512);
    k_logsoftmax<<<1024, 256, 0, stream>>>(lp);
}